// Round 1
// baseline (11855.620 us; speedup 1.0000x reference)
//
#include <hip/hip_runtime.h>
#include <cstdint>
#include <cstddef>

#define S_LEN 512
#define BATCH 32
#define IN0   256
#define HID   512
#define G3    1536        // 3*HID
#define VOCAB 10000
#define MTOK  (S_LEN * BATCH)   // 16384

typedef __attribute__((ext_vector_type(8))) short short8;
typedef __attribute__((ext_vector_type(4))) float f32x4;

__device__ __forceinline__ float bf2f(unsigned short u) {
    union { unsigned int i; float f; } v; v.i = ((unsigned int)u) << 16; return v.f;
}
__device__ __forceinline__ unsigned short f2bf(float f) {
    unsigned int u = __float_as_uint(f);
    u += 0x7fff + ((u >> 16) & 1);   // RNE (finite inputs only)
    return (unsigned short)(u >> 16);
}

// ---------------------------------------------------------------- cvt f32->bf16
__global__ void cvt_f32_bf16_k(const float* __restrict__ src,
                               unsigned short* __restrict__ dst, long n4) {
    long i = (long)blockIdx.x * blockDim.x + threadIdx.x;
    long stride = (long)gridDim.x * blockDim.x;
    for (; i < n4; i += stride) {
        float4 v = ((const float4*)src)[i];
        ushort4 o;
        o.x = f2bf(v.x); o.y = f2bf(v.y); o.z = f2bf(v.z); o.w = f2bf(v.w);
        ((ushort4*)dst)[i] = o;
    }
}

__global__ void zero_ints_k(int* p, int n) {
    int i = threadIdx.x;
    if (i < n) p[i] = 0;
}

// ---------------------------------------------------------------- GEMM (NT, bf16 in, MFMA)
// A: M x K (row-major, bf16), B: Nt x K (row-major, bf16) -> C = A*B^T
// EPI 0: out = bf16 xp scatter [dir][s][b][g] with bias (Nt==3072)
// EPI 1: out = f32 logits, row-major M x Nt, + bias, Nt=10000 (bounds-checked)
template<int EPI>
__global__ __launch_bounds__(256) void gemm_nt(
    const unsigned short* __restrict__ A,
    const unsigned short* __restrict__ B,
    const float* __restrict__ bias,
    void* __restrict__ out,
    int M, int Nt, int K)
{
    __shared__ alignas(16) unsigned short lA[128 * 32];
    __shared__ alignas(16) unsigned short lB[128 * 32];
    const int t = threadIdx.x;
    const int lane = t & 63, wave = t >> 6;
    const int wm = wave >> 1, wn = wave & 1;
    const int m0 = blockIdx.x * 128, n0 = blockIdx.y * 128;

    f32x4 acc[4][4] = {};
    const int nk = K >> 5;
    for (int kt = 0; kt < nk; ++kt) {
        const int k0 = kt << 5;
        __syncthreads();                        // previous iter's LDS reads done
        #pragma unroll
        for (int rnd = 0; rnd < 2; ++rnd) {
            int c = rnd * 256 + t;              // 16B chunk id, 0..511
            int row = c >> 2, kp = (c & 3) << 3;
            short8 va = *(const short8*)(A + (size_t)(m0 + row) * K + k0 + kp);
            int rn = n0 + row;
            if (EPI == 1) rn = rn < Nt ? rn : Nt - 1;
            short8 vb = *(const short8*)(B + (size_t)rn * K + k0 + kp);
            *(short8*)(lA + (size_t)c * 8) = va;
            *(short8*)(lB + (size_t)c * 8) = vb;
        }
        __syncthreads();
        short8 af[4], bf[4];
        #pragma unroll
        for (int f = 0; f < 4; ++f) {
            int ro = (wm * 64 + f * 16 + (lane & 15)) * 32 + ((lane >> 4) << 3);
            af[f] = *(const short8*)(lA + ro);
            int co = (wn * 64 + f * 16 + (lane & 15)) * 32 + ((lane >> 4) << 3);
            bf[f] = *(const short8*)(lB + co);
        }
        #pragma unroll
        for (int i = 0; i < 4; ++i)
            #pragma unroll
            for (int j = 0; j < 4; ++j)
                acc[i][j] = __builtin_amdgcn_mfma_f32_16x16x32_bf16(af[i], bf[j], acc[i][j], 0, 0, 0);
    }

    #pragma unroll
    for (int i = 0; i < 4; ++i) {
        #pragma unroll
        for (int j = 0; j < 4; ++j) {
            #pragma unroll
            for (int r = 0; r < 4; ++r) {
                int m = m0 + wm * 64 + i * 16 + ((lane >> 4) << 2) + r;
                int n = n0 + wn * 64 + j * 16 + (lane & 15);
                float v = acc[i][j][r];
                if (EPI == 0) {
                    int dir = n >= G3;
                    int g = n - dir * G3;
                    int s = m >> 5, b = m & 31;
                    v += bias[n];
                    ((unsigned short*)out)[(((size_t)dir * S_LEN + s) * BATCH + b) * G3 + g] = f2bf(v);
                } else {
                    if (n < Nt)
                        ((float*)out)[(size_t)m * Nt + n] = v + bias[n];
                }
            }
        }
    }
}

// ---------------------------------------------------------------- GRU layer (persistent, 16 blocks)
// grid: 16 blocks x 256 threads. dir = bid>>3, slice = bid&7 (64 j's each).
// W_hh slice lives in VGPRs for the whole 512-step scan.
__global__ __launch_bounds__(256, 1) void gru_layer_k(
    const unsigned short* __restrict__ xp,   // [2][S][B][G3] bf16 (includes b_ih)
    const unsigned short* __restrict__ whh,  // [2][G3][HID] bf16
    const float* __restrict__ bhh,           // [2][G3]
    const float* __restrict__ h0,            // [4][B][HID] (d_in h)
    unsigned short* __restrict__ y,          // [S][B][2*HID] bf16
    float* __restrict__ hN,                  // [2][B][HID] (this layer's slice of d_out tail)
    unsigned short* __restrict__ hb,         // [2 dir][2 buf][B][HID] bf16
    int* __restrict__ ctr,                   // [2] (this layer's counters)
    int layer)
{
    const int t = threadIdx.x;
    const int lane = t & 63, wave = t >> 6;
    const int dir = blockIdx.x >> 3, slice = blockIdx.x & 7;
    const int jw0 = slice * 64 + wave * 16;
    const int jl = jw0 + (lane & 15);
    const int bq = (lane >> 4) << 2;          // batch quad base within 16-row frag

    // ---- preload W_hh fragments into registers (B operand): Bf[ks][gate]
    short8 Bf[16][3];
    #pragma unroll
    for (int ks = 0; ks < 16; ++ks)
        #pragma unroll
        for (int g = 0; g < 3; ++g) {
            int ncol = g * HID + jl;
            Bf[ks][g] = *(const short8*)(whh + ((size_t)(dir * G3 + ncol)) * HID
                                              + ks * 32 + ((lane >> 4) << 3));
        }

    float bh[3];
    #pragma unroll
    for (int g = 0; g < 3; ++g) bh[g] = bhh[dir * G3 + g * HID + jl];

    // ---- own h slice in fp32 registers
    float hreg[2][4];
    #pragma unroll
    for (int m = 0; m < 2; ++m)
        #pragma unroll
        for (int r = 0; r < 4; ++r) {
            int b = m * 16 + bq + r;
            hreg[m][r] = h0[((size_t)(2 * layer + dir) * BATCH + b) * HID + jl];
        }

    unsigned short* hb_d = hb + (size_t)dir * 2 * BATCH * HID;
    #pragma unroll
    for (int m = 0; m < 2; ++m)
        #pragma unroll
        for (int r = 0; r < 4; ++r) {
            int b = m * 16 + bq + r;
            hb_d[(size_t)b * HID + jl] = f2bf(hreg[m][r]);
        }

    int* myctr = ctr + dir;
    auto barrier = [&](int target) {
        __syncthreads();
        if (t == 0) {
            __hip_atomic_fetch_add(myctr, 1, __ATOMIC_RELEASE, __HIP_MEMORY_SCOPE_AGENT);
            while (__hip_atomic_load(myctr, __ATOMIC_ACQUIRE, __HIP_MEMORY_SCOPE_AGENT) < target)
                __builtin_amdgcn_s_sleep(1);
        }
        __syncthreads();
    };
    int sync_idx = 1;
    barrier(8 * sync_idx); ++sync_idx;        // h0 published

    for (int st = 0; st < S_LEN; ++st) {
        const int tt = dir ? (S_LEN - 1 - st) : st;
        const int cur = st & 1, nxt = cur ^ 1;
        const unsigned short* hcur = hb_d + (size_t)cur * BATCH * HID;

        // issue all A-frag loads (h for all batches)
        short8 Af0[8][2], Af1[8][2];
        #pragma unroll
        for (int ks = 0; ks < 8; ++ks)
            #pragma unroll
            for (int m = 0; m < 2; ++m)
                Af0[ks][m] = *(const short8*)(hcur + (size_t)(m * 16 + (lane & 15)) * HID
                                                   + ks * 32 + ((lane >> 4) << 3));
        #pragma unroll
        for (int ks = 0; ks < 8; ++ks)
            #pragma unroll
            for (int m = 0; m < 2; ++m)
                Af1[ks][m] = *(const short8*)(hcur + (size_t)(m * 16 + (lane & 15)) * HID
                                                   + (ks + 8) * 32 + ((lane >> 4) << 3));

        // xp gate values (independent of h) — issue alongside
        float xg[2][4][3];
        #pragma unroll
        for (int m = 0; m < 2; ++m)
            #pragma unroll
            for (int r = 0; r < 4; ++r) {
                int b = m * 16 + bq + r;
                const unsigned short* xpb = xp + (((size_t)dir * S_LEN + tt) * BATCH + b) * G3 + jl;
                #pragma unroll
                for (int g = 0; g < 3; ++g) xg[m][r][g] = bf2f(xpb[g * HID]);
            }

        f32x4 acc[2][3] = {};
        #pragma unroll
        for (int ks = 0; ks < 8; ++ks)
            #pragma unroll
            for (int m = 0; m < 2; ++m)
                #pragma unroll
                for (int g = 0; g < 3; ++g)
                    acc[m][g] = __builtin_amdgcn_mfma_f32_16x16x32_bf16(Af0[ks][m], Bf[ks][g], acc[m][g], 0, 0, 0);
        #pragma unroll
        for (int ks = 0; ks < 8; ++ks)
            #pragma unroll
            for (int m = 0; m < 2; ++m)
                #pragma unroll
                for (int g = 0; g < 3; ++g)
                    acc[m][g] = __builtin_amdgcn_mfma_f32_16x16x32_bf16(Af1[ks][m], Bf[ks + 8][g], acc[m][g], 0, 0, 0);

        unsigned short* hnx = hb_d + (size_t)nxt * BATCH * HID;
        #pragma unroll
        for (int m = 0; m < 2; ++m)
            #pragma unroll
            for (int r = 0; r < 4; ++r) {
                int b = m * 16 + bq + r;
                float rr = 1.f / (1.f + __expf(-(xg[m][r][0] + acc[m][0][r] + bh[0])));
                float zz = 1.f / (1.f + __expf(-(xg[m][r][1] + acc[m][1][r] + bh[1])));
                float ni = xg[m][r][2] + rr * (acc[m][2][r] + bh[2]);
                ni = fminf(fmaxf(ni, -15.f), 15.f);
                float e = __expf(2.f * ni);
                float nn = (e - 1.f) / (e + 1.f);
                float hnew = (1.f - zz) * nn + zz * hreg[m][r];
                hreg[m][r] = hnew;
                hnx[(size_t)b * HID + jl] = f2bf(hnew);
                y[((size_t)tt * BATCH + b) * (2 * HID) + dir * HID + jl] = f2bf(hnew);
                if (st == S_LEN - 1)
                    hN[((size_t)dir * BATCH + b) * HID + jl] = hnew;
            }
        barrier(8 * sync_idx); ++sync_idx;
    }
}

// ---------------------------------------------------------------- row softmax (in-place, LDS-staged)
__global__ __launch_bounds__(256) void softmax_rows_k(float* __restrict__ io) {
    __shared__ float buf[VOCAB];
    __shared__ float red[8];
    const int row = blockIdx.x;
    float* p = io + (size_t)row * VOCAB;
    const int t = threadIdx.x;

    float lmax = -1e30f;
    for (int v = t; v < VOCAB; v += 256) { float f = p[v]; buf[v] = f; lmax = fmaxf(lmax, f); }
    #pragma unroll
    for (int o = 32; o > 0; o >>= 1) lmax = fmaxf(lmax, __shfl_xor(lmax, o, 64));
    if ((t & 63) == 0) red[t >> 6] = lmax;
    __syncthreads();
    float mx = fmaxf(fmaxf(red[0], red[1]), fmaxf(red[2], red[3]));

    float lsum = 0.f;
    for (int v = t; v < VOCAB; v += 256) { float e = __expf(buf[v] - mx); buf[v] = e; lsum += e; }
    #pragma unroll
    for (int o = 32; o > 0; o >>= 1) lsum += __shfl_xor(lsum, o, 64);
    __syncthreads();
    if ((t & 63) == 0) red[t >> 6] = lsum;
    __syncthreads();
    float inv = 1.f / (red[0] + red[1] + red[2] + red[3]);
    for (int v = t; v < VOCAB; v += 256) p[v] = buf[v] * inv;
}

// ---------------------------------------------------------------- launch
extern "C" void kernel_launch(void* const* d_in, const int* in_sizes, int n_in,
                              void* d_out, int out_size, void* d_ws, size_t ws_size,
                              hipStream_t stream) {
    const float* feat  = (const float*)d_in[0];
    const float* h_in  = (const float*)d_in[1];
    const float* W_ih0 = (const float*)d_in[2];
    const float* W_hh0 = (const float*)d_in[3];
    const float* b_ih0 = (const float*)d_in[4];
    const float* b_hh0 = (const float*)d_in[5];
    const float* W_ih1 = (const float*)d_in[6];
    const float* W_hh1 = (const float*)d_in[7];
    const float* b_ih1 = (const float*)d_in[8];
    const float* b_hh1 = (const float*)d_in[9];
    const float* W_lin = (const float*)d_in[10];
    const float* b_lin = (const float*)d_in[11];
    float* out = (float*)d_out;

    char* ws = (char*)d_ws;
    unsigned short* fb16 = (unsigned short*)(ws + 0);            // 16384*256
    unsigned short* w0i  = (unsigned short*)(ws + 8388608);      // 2*1536*256
    unsigned short* w0h  = (unsigned short*)(ws + 9961472);      // 2*1536*512
    unsigned short* w1i  = (unsigned short*)(ws + 13107200);     // 2*1536*1024
    unsigned short* w1h  = (unsigned short*)(ws + 19398656);     // 2*1536*512
    unsigned short* wl   = (unsigned short*)(ws + 22544384);     // 10000*1024
    unsigned short* xp   = (unsigned short*)(ws + 43024384);     // 2*512*32*1536 (reused per layer)
    unsigned short* y0   = (unsigned short*)(ws + 143687680);    // 16384*1024
    unsigned short* y1   = (unsigned short*)(ws + 177242112);    // 16384*1024
    unsigned short* hb   = (unsigned short*)(ws + 210796544);    // 2*2*32*512
    int*            ctr  = (int*)(ws + 210927616);               // 16 ints

    float* hN_base = out + (size_t)MTOK * VOCAB;                 // d_out tail: (2L,B,H)

    zero_ints_k<<<1, 32, 0, stream>>>(ctr, 16);
    cvt_f32_bf16_k<<<2048, 256, 0, stream>>>(feat,  fb16, (long)MTOK * IN0 / 4);
    cvt_f32_bf16_k<<<2048, 256, 0, stream>>>(W_ih0, w0i,  (long)2 * G3 * IN0 / 4);
    cvt_f32_bf16_k<<<2048, 256, 0, stream>>>(W_hh0, w0h,  (long)2 * G3 * HID / 4);
    cvt_f32_bf16_k<<<2048, 256, 0, stream>>>(W_ih1, w1i,  (long)2 * G3 * 2 * HID / 4);
    cvt_f32_bf16_k<<<2048, 256, 0, stream>>>(W_hh1, w1h,  (long)2 * G3 * HID / 4);
    cvt_f32_bf16_k<<<2048, 256, 0, stream>>>(W_lin, wl,   (long)VOCAB * 2 * HID / 4);

    // layer 0
    gemm_nt<0><<<dim3(MTOK / 128, 3072 / 128), 256, 0, stream>>>(fb16, w0i, b_ih0, xp, MTOK, 3072, IN0);
    gru_layer_k<<<16, 256, 0, stream>>>(xp, w0h, b_hh0, h_in, y0, hN_base, hb, ctr, 0);
    // layer 1
    gemm_nt<0><<<dim3(MTOK / 128, 3072 / 128), 256, 0, stream>>>(y0, w1i, b_ih1, xp, MTOK, 3072, 2 * HID);
    gru_layer_k<<<16, 256, 0, stream>>>(xp, w1h, b_hh1, h_in, y1, hN_base + (size_t)2 * BATCH * HID, hb, ctr + 2, 1);
    // final linear -> logits in d_out (in place), then softmax
    gemm_nt<1><<<dim3(MTOK / 128, (VOCAB + 127) / 128), 256, 0, stream>>>(y1, wl, b_lin, out, MTOK, VOCAB, 2 * HID);
    softmax_rows_k<<<MTOK, 256, 0, stream>>>(out);
}

// Round 2
// 9409.602 us; speedup vs baseline: 1.2599x; 1.2599x over previous
//
#include <hip/hip_runtime.h>
#include <cstdint>
#include <cstddef>

#define S_LEN 512
#define BATCH 32
#define IN0   256
#define HID   512
#define G3    1536        // 3*HID
#define VOCAB 10000
#define MTOK  (S_LEN * BATCH)   // 16384

typedef __attribute__((ext_vector_type(8))) short short8;
typedef __attribute__((ext_vector_type(4))) float f32x4;

__device__ __forceinline__ float bf2f(unsigned short u) {
    union { unsigned int i; float f; } v; v.i = ((unsigned int)u) << 16; return v.f;
}
__device__ __forceinline__ unsigned short f2bf(float f) {
    unsigned int u = __float_as_uint(f);
    u += 0x7fff + ((u >> 16) & 1);   // RNE (finite inputs only)
    return (unsigned short)(u >> 16);
}

// ---------------------------------------------------------------- cvt f32->bf16
__global__ void cvt_f32_bf16_k(const float* __restrict__ src,
                               unsigned short* __restrict__ dst, long n4) {
    long i = (long)blockIdx.x * blockDim.x + threadIdx.x;
    long stride = (long)gridDim.x * blockDim.x;
    for (; i < n4; i += stride) {
        float4 v = ((const float4*)src)[i];
        ushort4 o;
        o.x = f2bf(v.x); o.y = f2bf(v.y); o.z = f2bf(v.z); o.w = f2bf(v.w);
        ((ushort4*)dst)[i] = o;
    }
}

__global__ void zero_ints_k(int* p, int n) {
    int i = threadIdx.x;
    if (i < n) p[i] = 0;
}

// ---------------------------------------------------------------- GEMM (NT, bf16 in, MFMA)
// A: M x K (row-major, bf16), B: Nt x K (row-major, bf16) -> C = A*B^T
// EPI 0: out = bf16 xp scatter [dir][s][b][g] with bias (Nt==3072)
// EPI 1: out = f32 logits, row-major M x Nt, + bias, Nt=10000 (bounds-checked)
template<int EPI>
__global__ __launch_bounds__(256) void gemm_nt(
    const unsigned short* __restrict__ A,
    const unsigned short* __restrict__ B,
    const float* __restrict__ bias,
    void* __restrict__ out,
    int M, int Nt, int K)
{
    __shared__ alignas(16) unsigned short lA[128 * 32];
    __shared__ alignas(16) unsigned short lB[128 * 32];
    const int t = threadIdx.x;
    const int lane = t & 63, wave = t >> 6;
    const int wm = wave >> 1, wn = wave & 1;
    const int m0 = blockIdx.x * 128, n0 = blockIdx.y * 128;

    f32x4 acc[4][4] = {};
    const int nk = K >> 5;
    for (int kt = 0; kt < nk; ++kt) {
        const int k0 = kt << 5;
        __syncthreads();                        // previous iter's LDS reads done
        #pragma unroll
        for (int rnd = 0; rnd < 2; ++rnd) {
            int c = rnd * 256 + t;              // 16B chunk id, 0..511
            int row = c >> 2, kp = (c & 3) << 3;
            short8 va = *(const short8*)(A + (size_t)(m0 + row) * K + k0 + kp);
            int rn = n0 + row;
            if (EPI == 1) rn = rn < Nt ? rn : Nt - 1;
            short8 vb = *(const short8*)(B + (size_t)rn * K + k0 + kp);
            *(short8*)(lA + (size_t)c * 8) = va;
            *(short8*)(lB + (size_t)c * 8) = vb;
        }
        __syncthreads();
        short8 af[4], bf[4];
        #pragma unroll
        for (int f = 0; f < 4; ++f) {
            int ro = (wm * 64 + f * 16 + (lane & 15)) * 32 + ((lane >> 4) << 3);
            af[f] = *(const short8*)(lA + ro);
            int co = (wn * 64 + f * 16 + (lane & 15)) * 32 + ((lane >> 4) << 3);
            bf[f] = *(const short8*)(lB + co);
        }
        #pragma unroll
        for (int i = 0; i < 4; ++i)
            #pragma unroll
            for (int j = 0; j < 4; ++j)
                acc[i][j] = __builtin_amdgcn_mfma_f32_16x16x32_bf16(af[i], bf[j], acc[i][j], 0, 0, 0);
    }

    #pragma unroll
    for (int i = 0; i < 4; ++i) {
        #pragma unroll
        for (int j = 0; j < 4; ++j) {
            #pragma unroll
            for (int r = 0; r < 4; ++r) {
                int m = m0 + wm * 64 + i * 16 + ((lane >> 4) << 2) + r;
                int n = n0 + wn * 64 + j * 16 + (lane & 15);
                float v = acc[i][j][r];
                if (EPI == 0) {
                    int dir = n >= G3;
                    int g = n - dir * G3;
                    int s = m >> 5, b = m & 31;
                    v += bias[n];
                    ((unsigned short*)out)[(((size_t)dir * S_LEN + s) * BATCH + b) * G3 + g] = f2bf(v);
                } else {
                    if (n < Nt)
                        ((float*)out)[(size_t)m * Nt + n] = v + bias[n];
                }
            }
        }
    }
}

// ---------------------------------------------------------------- GRU layer (persistent, 16 blocks)
// grid: 16 blocks x 256 threads. dir = bid>>3, slice = bid&7 (64 j's each).
// W_hh slice lives in VGPRs for the whole 512-step scan.
// Cross-block h exchange: fine-grained coherent (sc0 sc1) loads/stores only —
// NO release/acquire fences (those emit per-step buffer_wbl2/buffer_inv = the
// R1 9.7us/step disaster). Per-wave flags (32/dir), no atomic RMW, no
// __syncthreads; ordering h-stores -> flag-store via s_waitcnt vmcnt(0).
__global__ __launch_bounds__(256, 1) void gru_layer_k(
    const unsigned short* __restrict__ xp,   // [2][S][B][G3] bf16 (includes b_ih)
    const unsigned short* __restrict__ whh,  // [2][G3][HID] bf16
    const float* __restrict__ bhh,           // [2][G3]
    const float* __restrict__ h0,            // [4][B][HID] (d_in h)
    unsigned short* __restrict__ y,          // [S][B][2*HID] bf16
    float* __restrict__ hN,                  // [2][B][HID] (this layer's slice of d_out tail)
    unsigned short* __restrict__ hb,         // [2 dir][2 buf][B][HID] bf16
    int* __restrict__ flg,                   // [2 dir][32 waves] this layer
    int layer)
{
    const int t = threadIdx.x;
    const int lane = t & 63, wave = t >> 6;
    const int dir = blockIdx.x >> 3, slice = blockIdx.x & 7;
    const int jl = slice * 64 + wave * 16 + (lane & 15);
    const int bq = (lane >> 4) << 2;          // batch quad base within 16-row frag

    // ---- preload W_hh fragments into registers (B operand): Bf[ks][gate]
    short8 Bf[16][3];
    #pragma unroll
    for (int ks = 0; ks < 16; ++ks)
        #pragma unroll
        for (int g = 0; g < 3; ++g)
            Bf[ks][g] = *(const short8*)(whh + (size_t)(dir * G3 + g * HID + jl) * HID
                                              + ks * 32 + ((lane >> 4) << 3));

    float bh[3];
    #pragma unroll
    for (int g = 0; g < 3; ++g) bh[g] = bhh[dir * G3 + g * HID + jl];

    // ---- own h slice in fp32 registers
    float hreg[2][4];
    #pragma unroll
    for (int m = 0; m < 2; ++m)
        #pragma unroll
        for (int r = 0; r < 4; ++r) {
            int b = m * 16 + bq + r;
            hreg[m][r] = h0[((size_t)(2 * layer + dir) * BATCH + b) * HID + jl];
        }

    unsigned short* hb_d = hb + (size_t)dir * 2 * BATCH * HID;
    int* flg_d = flg + dir * 32;
    int* myflag = flg_d + slice * 4 + wave;

    // ---- publish h0 into buf0 (coherent stores), then flag=1
    #pragma unroll
    for (int m = 0; m < 2; ++m)
        #pragma unroll
        for (int r = 0; r < 4; ++r) {
            int b = m * 16 + bq + r;
            unsigned int v = f2bf(hreg[m][r]);
            const unsigned short* p = hb_d + (size_t)b * HID + jl;
            asm volatile("global_store_short %0, %1, off sc0 sc1" :: "v"(p), "v"(v) : "memory");
        }
    asm volatile("s_waitcnt vmcnt(0)" ::: "memory");
    if (lane == 0) {
        int one = 1;
        asm volatile("global_store_dword %0, %1, off sc0 sc1" :: "v"(myflag), "v"(one) : "memory");
    }

    // ---- prefetch xp for step 0
    float xg[2][4][3], xgn[2][4][3];
    {
        const int tt0 = dir ? (S_LEN - 1) : 0;
        #pragma unroll
        for (int m = 0; m < 2; ++m)
            #pragma unroll
            for (int r = 0; r < 4; ++r) {
                int b = m * 16 + bq + r;
                const unsigned short* xpb = xp + (((size_t)dir * S_LEN + tt0) * BATCH + b) * G3 + jl;
                #pragma unroll
                for (int g = 0; g < 3; ++g) xg[m][r][g] = bf2f(xpb[g * HID]);
            }
    }

    for (int st = 0; st < S_LEN; ++st) {
        // ---- wait until all 32 waves of this dir published h(st)
        {
            const int* fp = flg_d + (lane & 31);
            const int target = st + 1;
            int v;
            do {
                asm volatile("global_load_dword %0, %1, off sc0 sc1\n\t"
                             "s_waitcnt vmcnt(0)"
                             : "=v"(v) : "v"(fp) : "memory");
            } while (__any(v < target));
        }
        __builtin_amdgcn_sched_barrier(0);

        // ---- load h(st) A-fragments (coherent b128)
        const unsigned short* hcur = hb_d + (size_t)(st & 1) * BATCH * HID;
        short8 Af[16][2];
        #pragma unroll
        for (int ks = 0; ks < 16; ++ks)
            #pragma unroll
            for (int m = 0; m < 2; ++m) {
                const unsigned short* p = hcur + (size_t)(m * 16 + (lane & 15)) * HID
                                               + ks * 32 + ((lane >> 4) << 3);
                asm volatile("global_load_dwordx4 %0, %1, off sc0 sc1"
                             : "=v"(Af[ks][m]) : "v"(p));
            }
        asm volatile("s_waitcnt vmcnt(0)" ::: "memory");
        __builtin_amdgcn_sched_barrier(0);

        // ---- gate GEMM
        f32x4 acc[2][3] = {};
        #pragma unroll
        for (int ks = 0; ks < 16; ++ks)
            #pragma unroll
            for (int m = 0; m < 2; ++m)
                #pragma unroll
                for (int g = 0; g < 3; ++g)
                    acc[m][g] = __builtin_amdgcn_mfma_f32_16x16x32_bf16(Af[ks][m], Bf[ks][g], acc[m][g], 0, 0, 0);

        // ---- epilogue: gates, h update, publish h(st+1)
        const int tt = dir ? (S_LEN - 1 - st) : st;
        unsigned short* hnx = hb_d + (size_t)((st + 1) & 1) * BATCH * HID;
        #pragma unroll
        for (int m = 0; m < 2; ++m)
            #pragma unroll
            for (int r = 0; r < 4; ++r) {
                int b = m * 16 + bq + r;
                float rr = 1.f / (1.f + __expf(-(xg[m][r][0] + acc[m][0][r] + bh[0])));
                float zz = 1.f / (1.f + __expf(-(xg[m][r][1] + acc[m][1][r] + bh[1])));
                float ni = xg[m][r][2] + rr * (acc[m][2][r] + bh[2]);
                ni = fminf(fmaxf(ni, -15.f), 15.f);
                float e = __expf(2.f * ni);
                float nn = (e - 1.f) / (e + 1.f);
                float hnew = (1.f - zz) * nn + zz * hreg[m][r];
                hreg[m][r] = hnew;
                unsigned int hv = f2bf(hnew);
                const unsigned short* p = hnx + (size_t)b * HID + jl;
                asm volatile("global_store_short %0, %1, off sc0 sc1" :: "v"(p), "v"(hv) : "memory");
            }
        asm volatile("s_waitcnt vmcnt(0)" ::: "memory");
        if (lane == 0) {
            int tv = st + 2;
            asm volatile("global_store_dword %0, %1, off sc0 sc1" :: "v"(myflag), "v"(tv) : "memory");
        }

        // ---- off-critical-path: y (+ hN on last step), next-step xp prefetch
        #pragma unroll
        for (int m = 0; m < 2; ++m)
            #pragma unroll
            for (int r = 0; r < 4; ++r) {
                int b = m * 16 + bq + r;
                y[((size_t)tt * BATCH + b) * (2 * HID) + dir * HID + jl] = f2bf(hreg[m][r]);
                if (st == S_LEN - 1)
                    hN[((size_t)dir * BATCH + b) * HID + jl] = hreg[m][r];
            }
        {
            const int stn = (st + 1 < S_LEN) ? st + 1 : st;
            const int ttn = dir ? (S_LEN - 1 - stn) : stn;
            #pragma unroll
            for (int m = 0; m < 2; ++m)
                #pragma unroll
                for (int r = 0; r < 4; ++r) {
                    int b = m * 16 + bq + r;
                    const unsigned short* xpb = xp + (((size_t)dir * S_LEN + ttn) * BATCH + b) * G3 + jl;
                    #pragma unroll
                    for (int g = 0; g < 3; ++g) xgn[m][r][g] = bf2f(xpb[g * HID]);
                }
        }
        #pragma unroll
        for (int m = 0; m < 2; ++m)
            #pragma unroll
            for (int r = 0; r < 4; ++r)
                #pragma unroll
                for (int g = 0; g < 3; ++g) xg[m][r][g] = xgn[m][r][g];
    }
}

// ---------------------------------------------------------------- row softmax (in-place, LDS-staged)
__global__ __launch_bounds__(256) void softmax_rows_k(float* __restrict__ io) {
    __shared__ float buf[VOCAB];
    __shared__ float red[8];
    const int row = blockIdx.x;
    float* p = io + (size_t)row * VOCAB;
    const int t = threadIdx.x;

    float lmax = -1e30f;
    for (int v = t; v < VOCAB; v += 256) { float f = p[v]; buf[v] = f; lmax = fmaxf(lmax, f); }
    #pragma unroll
    for (int o = 32; o > 0; o >>= 1) lmax = fmaxf(lmax, __shfl_xor(lmax, o, 64));
    if ((t & 63) == 0) red[t >> 6] = lmax;
    __syncthreads();
    float mx = fmaxf(fmaxf(red[0], red[1]), fmaxf(red[2], red[3]));

    float lsum = 0.f;
    for (int v = t; v < VOCAB; v += 256) { float e = __expf(buf[v] - mx); buf[v] = e; lsum += e; }
    #pragma unroll
    for (int o = 32; o > 0; o >>= 1) lsum += __shfl_xor(lsum, o, 64);
    __syncthreads();
    if ((t & 63) == 0) red[t >> 6] = lsum;
    __syncthreads();
    float inv = 1.f / (red[0] + red[1] + red[2] + red[3]);
    for (int v = t; v < VOCAB; v += 256) p[v] = buf[v] * inv;
}

// ---------------------------------------------------------------- launch
extern "C" void kernel_launch(void* const* d_in, const int* in_sizes, int n_in,
                              void* d_out, int out_size, void* d_ws, size_t ws_size,
                              hipStream_t stream) {
    const float* feat  = (const float*)d_in[0];
    const float* h_in  = (const float*)d_in[1];
    const float* W_ih0 = (const float*)d_in[2];
    const float* W_hh0 = (const float*)d_in[3];
    const float* b_ih0 = (const float*)d_in[4];
    const float* b_hh0 = (const float*)d_in[5];
    const float* W_ih1 = (const float*)d_in[6];
    const float* W_hh1 = (const float*)d_in[7];
    const float* b_ih1 = (const float*)d_in[8];
    const float* b_hh1 = (const float*)d_in[9];
    const float* W_lin = (const float*)d_in[10];
    const float* b_lin = (const float*)d_in[11];
    float* out = (float*)d_out;

    char* ws = (char*)d_ws;
    unsigned short* fb16 = (unsigned short*)(ws + 0);            // 16384*256
    unsigned short* w0i  = (unsigned short*)(ws + 8388608);      // 2*1536*256
    unsigned short* w0h  = (unsigned short*)(ws + 9961472);      // 2*1536*512
    unsigned short* w1i  = (unsigned short*)(ws + 13107200);     // 2*1536*1024
    unsigned short* w1h  = (unsigned short*)(ws + 19398656);     // 2*1536*512
    unsigned short* wl   = (unsigned short*)(ws + 22544384);     // 10000*1024
    unsigned short* xp   = (unsigned short*)(ws + 43024384);     // 2*512*32*1536 (reused per layer)
    unsigned short* y0   = (unsigned short*)(ws + 143687680);    // 16384*1024
    unsigned short* y1   = (unsigned short*)(ws + 177242112);    // 16384*1024
    unsigned short* hb   = (unsigned short*)(ws + 210796544);    // 2*2*32*512
    int*            flg  = (int*)(ws + 210927616);               // 2 layers * 64 ints

    float* hN_base = out + (size_t)MTOK * VOCAB;                 // d_out tail: (2L,B,H)

    zero_ints_k<<<1, 128, 0, stream>>>(flg, 128);
    cvt_f32_bf16_k<<<2048, 256, 0, stream>>>(feat,  fb16, (long)MTOK * IN0 / 4);
    cvt_f32_bf16_k<<<2048, 256, 0, stream>>>(W_ih0, w0i,  (long)2 * G3 * IN0 / 4);
    cvt_f32_bf16_k<<<2048, 256, 0, stream>>>(W_hh0, w0h,  (long)2 * G3 * HID / 4);
    cvt_f32_bf16_k<<<2048, 256, 0, stream>>>(W_ih1, w1i,  (long)2 * G3 * 2 * HID / 4);
    cvt_f32_bf16_k<<<2048, 256, 0, stream>>>(W_hh1, w1h,  (long)2 * G3 * HID / 4);
    cvt_f32_bf16_k<<<2048, 256, 0, stream>>>(W_lin, wl,   (long)VOCAB * 2 * HID / 4);

    // layer 0
    gemm_nt<0><<<dim3(MTOK / 128, 3072 / 128), 256, 0, stream>>>(fb16, w0i, b_ih0, xp, MTOK, 3072, IN0);
    gru_layer_k<<<16, 256, 0, stream>>>(xp, w0h, b_hh0, h_in, y0, hN_base, hb, flg, 0);
    // layer 1
    gemm_nt<0><<<dim3(MTOK / 128, 3072 / 128), 256, 0, stream>>>(y0, w1i, b_ih1, xp, MTOK, 3072, 2 * HID);
    gru_layer_k<<<16, 256, 0, stream>>>(xp, w1h, b_hh1, h_in, y1, hN_base + (size_t)2 * BATCH * HID, hb, flg + 64, 1);
    // final linear -> logits in d_out (in place), then softmax
    gemm_nt<1><<<dim3(MTOK / 128, (VOCAB + 127) / 128), 256, 0, stream>>>(y1, wl, b_lin, out, MTOK, VOCAB, 2 * HID);
    softmax_rows_k<<<MTOK, 256, 0, stream>>>(out);
}